// Round 1
// baseline (266.080 us; speedup 1.0000x reference)
//
#include <hip/hip_runtime.h>
#include <cstdint>
#include <cstddef>

#define NN 30000
#define NE 480000
#define NG 128
#define DIN 128
#define DH 256
#define NC 60
#define CAP 64               // bucket capacity per node (true deg ~ Poisson(16); P(>64) ~ 1e-20)
#define P1MAX (NN * DIN / 4) // 960000: widest job in pre phase

typedef _Float16 f16x8 __attribute__((ext_vector_type(8)));
typedef _Float16 half4_t __attribute__((ext_vector_type(4)));
typedef float f32x4 __attribute__((ext_vector_type(4)));

// async global->LDS, 16B per lane (wave-uniform base + lane*16 dest required)
__device__ __forceinline__ void gload_lds16(const _Float16* g, _Float16* l) {
    __builtin_amdgcn_global_load_lds(
        (const __attribute__((address_space(1))) void*)g,
        (__attribute__((address_space(3))) void*)l, 16, 0, 0);
}

// ---------------- fused pre: bucket edges + x->fp16 + W->fp16 + zero sums ----------------
__global__ __launch_bounds__(256) void k_pre(const int* __restrict__ ei, int* __restrict__ cursor,
        int* __restrict__ csr_src,
        const float* __restrict__ x, _Float16* __restrict__ xh,
        const float* __restrict__ W1, const float* __restrict__ W2, const float* __restrict__ W3,
        _Float16* __restrict__ w1h, _Float16* __restrict__ w2h, _Float16* __restrict__ w3h,
        float* __restrict__ sums) {
    int i = blockIdx.x * 256 + threadIdx.x;
    if (i < NE) {
        int s = ei[i];        // edge_index[0]
        int d = ei[NE + i];   // edge_index[1]
        int slot = atomicAdd(&cursor[d], 1);
        if (slot < CAP) csr_src[d * CAP + slot] = s;
    }
    if (i < P1MAX) {
        float4 v = ((const float4*)x)[i];
        half4_t o;
        o[0] = (_Float16)v.x; o[1] = (_Float16)v.y;
        o[2] = (_Float16)v.z; o[3] = (_Float16)v.w;
        ((half4_t*)xh)[i] = o;
    }
    if (i < DH * DIN) w1h[i] = (_Float16)W1[i];
    if (i < DH * DH) {
        w2h[i] = (_Float16)W2[i];
        w3h[i] = (_Float16)W3[i];
    }
    if (i < NG * DH) sums[i] = 0.f;
}

// ---------------- aggregation: u[v] = sum_e w_e*hin[src_e] + hin[v]/(deg_v+1) ----------------
// One wave per node. 16B/lane gathers: wave splits into G = 64/(K/8) lane-groups, each
// group owns one edge of the current batch -> halves VMEM and VALU instruction count per
// edge vs the 8B/lane layout. Cross-group butterfly reduce at the end (log2(G) shfl_xor
// stages over 8 fp32). fp16 plane in/out, fp32 accumulate.
template<int K>
__global__ __launch_bounds__(256) void k_agg(const _Float16* __restrict__ hin,
        _Float16* __restrict__ tout, const int* __restrict__ cnt,
        const int* __restrict__ csr_src) {
    constexpr int L = K / 8;   // lanes per row (16B chunks per row)
    constexpr int G = 64 / L;  // edges processed per wave-wide load (2 for K=256, 4 for K=128)
    int node = blockIdx.x * 4 + (threadIdx.x >> 6);
    int lane = threadIdx.x & 63;
    int sub = lane / L;        // which edge of the group this lane serves
    int off = lane % L;        // 8-half chunk index within the row
    const _Float16* gbase = hin + off * 8;
    float acc[8];
    #pragma unroll
    for (int u = 0; u < 8; u++) acc[u] = 0.f;
    int deg = cnt[node];
    float dvd = rsqrtf((float)(deg + 1));
    int c = deg < CAP ? deg : CAP;
    int beg = node * CAP, end = beg + c;
    int e = beg;
    // main: 4 group-batches (4*G edges) in flight for MLP
    for (; e + 4 * G <= end; e += 4 * G) {
        int s[4]; float w[4]; f16x8 r[4];
        #pragma unroll
        for (int j = 0; j < 4; j++) s[j] = csr_src[e + j * G + sub];
        #pragma unroll
        for (int j = 0; j < 4; j++) w[j] = rsqrtf((float)(cnt[s[j]] + 1)) * dvd;
        #pragma unroll
        for (int j = 0; j < 4; j++) r[j] = *(const f16x8*)(gbase + (size_t)s[j] * K);
        #pragma unroll
        for (int j = 0; j < 4; j++)
            #pragma unroll
            for (int u = 0; u < 8; u++) acc[u] = fmaf(w[j], (float)r[j][u], acc[u]);
    }
    // tail: one group at a time; idle lanes get weight 0 on a safe (self) row
    for (; e < end; e += G) {
        int idx = e + sub;
        int s0 = node; float w0 = 0.f;
        if (idx < end) { s0 = csr_src[idx]; w0 = rsqrtf((float)(cnt[s0] + 1)) * dvd; }
        f16x8 r0 = *(const f16x8*)(gbase + (size_t)s0 * K);
        #pragma unroll
        for (int u = 0; u < 8; u++) acc[u] = fmaf(w0, (float)r0[u], acc[u]);
    }
    // self loop: weight 1/(deg+1), counted once (only sub==0 lanes add it)
    {
        float sws = (sub == 0) ? dvd * dvd : 0.f;
        f16x8 rs = *(const f16x8*)(gbase + (size_t)node * K);
        #pragma unroll
        for (int u = 0; u < 8; u++) acc[u] = fmaf(sws, (float)rs[u], acc[u]);
    }
    // butterfly reduce across the G lane-groups (same 'off' in partners)
    #pragma unroll
    for (int u = 0; u < 8; u++) {
        float v = acc[u];
        #pragma unroll
        for (int m = L; m < 64; m <<= 1) v += __shfl_xor(v, m, 64);
        acc[u] = v;
    }
    if (sub == 0) {
        f16x8 o;
        #pragma unroll
        for (int u = 0; u < 8; u++) o[u] = (_Float16)acc[u];
        *(f16x8*)(tout + (size_t)node * K + off * 8) = o;
    }
}

// ---------------- fp16 MFMA GEMM: C[M x 256] = relu(A * W^T + bias) ----------------
// BM=64 x BN=64, BK=32, 4 waves, wave tile 32x32 (2x2 of 16x16x32).
// Tile shrunk from 128x128: grid (469,4)=1876 blocks -> ~7.3 blocks/CU (~7 waves/SIMD)
// vs the old 470 blocks at ~1.8 waves/SIMD. The 2-barrier K-loop is latency-exposed at
// low occupancy; this trades 2x A-tile L2 re-reads (~+30MB, cheap) for 4x latency hiding.
// Staging: one global_load_lds width=16 per matrix per thread per K-step; LDS stride 32
// halves UNPADDED (lane-contiguous dest constraint; thread t's 16B lands at t*16 B).
// FUSE_POOL=true (layer 3): epilogue run-sums per graph (batch sorted) -> atomicAdd.
template<int K, bool FUSE_POOL>
__global__ __launch_bounds__(256) void k_gemm(const _Float16* __restrict__ A,
        const _Float16* __restrict__ W, const float* __restrict__ bias,
        _Float16* __restrict__ Cb, const int* __restrict__ batch,
        float* __restrict__ sums) {
    __shared__ __align__(16) _Float16 lsA[64 * 32];
    __shared__ __align__(16) _Float16 lsB[64 * 32];
    int t = threadIdx.x;
    int bm = blockIdx.x * 64;
    int bn = blockIdx.y * 64;
    int lane = t & 63, wv = t >> 6;
    int wm = (wv & 1) * 32;
    int wn = (wv >> 1) * 32;
    int lm = lane & 15, q = lane >> 4;
    int r4 = t >> 2;
    int c4 = t & 3;
    int ra = bm + r4; if (ra >= NN) ra = NN - 1;
    int rb = bn + r4;

    f32x4 acc[2][2];
    #pragma unroll
    for (int i = 0; i < 2; i++)
        #pragma unroll
        for (int j = 0; j < 2; j++) acc[i][j] = (f32x4){0.f, 0.f, 0.f, 0.f};

    for (int k0 = 0; k0 < K; k0 += 32) {
        size_t ko = (size_t)k0 + c4 * 8;
        __syncthreads();  // previous tile fully consumed before LDS overwrite
        // thread t -> LDS half-offset r4*32 + c4*8 == t*8 (lane-contiguous 16B chunks)
        gload_lds16(A + (size_t)ra * K + ko, lsA + t * 8);
        gload_lds16(W + (size_t)rb * K + ko, lsB + t * 8);
        __syncthreads();  // drains vmcnt (compiler inserts) + all lanes staged
        f16x8 bf[2];
        #pragma unroll
        for (int nt = 0; nt < 2; nt++)
            bf[nt] = *(const f16x8*)&lsB[(wn + nt * 16 + lm) * 32 + q * 8];
        #pragma unroll
        for (int mt = 0; mt < 2; mt++) {
            f16x8 af = *(const f16x8*)&lsA[(wm + mt * 16 + lm) * 32 + q * 8];
            #pragma unroll
            for (int nt = 0; nt < 2; nt++)
                acc[mt][nt] = __builtin_amdgcn_mfma_f32_16x16x32_f16(af, bf[nt], acc[mt][nt], 0, 0, 0);
        }
    }
    // epilogue: C/D layout col = lane&15, row = q*4 + r
    if constexpr (!FUSE_POOL) {
        #pragma unroll
        for (int mt = 0; mt < 2; mt++) {
            #pragma unroll
            for (int nt = 0; nt < 2; nt++) {
                int col = bn + wn + nt * 16 + lm;
                float bv = bias[col];
                #pragma unroll
                for (int r = 0; r < 4; r++) {
                    int row = bm + wm + mt * 16 + q * 4 + r;
                    if (row < NN) {
                        float v = fmaxf(acc[mt][nt][r] + bv, 0.f);
                        Cb[(size_t)row * 256 + col] = (_Float16)v;
                    }
                }
            }
        }
    } else {
        // graph ids for this lane's 8 rows (ascending; reused across nt)
        int gid[8];
        #pragma unroll
        for (int mt = 0; mt < 2; mt++)
            #pragma unroll
            for (int r = 0; r < 4; r++) {
                int row = bm + wm + mt * 16 + q * 4 + r;
                gid[mt * 4 + r] = (row < NN) ? batch[row] : -1;
            }
        #pragma unroll
        for (int nt = 0; nt < 2; nt++) {
            int col = bn + wn + nt * 16 + lm;
            float bv = bias[col];
            float runsum = 0.f;
            int curg = -1;
            #pragma unroll
            for (int mt = 0; mt < 2; mt++) {
                #pragma unroll
                for (int r = 0; r < 4; r++) {
                    int g = gid[mt * 4 + r];
                    if (g >= 0) {
                        float v = fmaxf(acc[mt][nt][r] + bv, 0.f);
                        if (g != curg) {
                            if (curg >= 0) atomicAdd(&sums[curg * DH + col], runsum);
                            curg = g;
                            runsum = 0.f;
                        }
                        runsum += v;
                    }
                }
            }
            if (curg >= 0) atomicAdd(&sums[curg * DH + col], runsum);
        }
    }
}

// ---------------- FC: out[G x 60] = (sums[g]/cnt) @ Wfc[60 x 256]^T + bfc ----------------
__global__ __launch_bounds__(64) void k_fc(const float* __restrict__ sums,
        const int* __restrict__ batch, const float* __restrict__ Wfc,
        const float* __restrict__ bfc, float* __restrict__ out) {
    __shared__ float p[DH];
    int g = blockIdx.x;
    int t = threadIdx.x;
    int lo = 0, hi = NN;
    while (lo < hi) { int mid = (lo + hi) >> 1; if (batch[mid] < g) lo = mid + 1; else hi = mid; }
    int start = lo;
    hi = NN;
    while (lo < hi) { int mid = (lo + hi) >> 1; if (batch[mid] < g + 1) lo = mid + 1; else hi = mid; }
    int cnt = lo - start;
    float inv = (cnt > 0) ? 1.f / (float)cnt : 0.f;
    for (int i = t; i < DH; i += 64) p[i] = sums[g * DH + i] * inv;
    __syncthreads();
    if (t < NC) {
        float a = bfc[t];
        for (int k = 0; k < DH; k++) a = fmaf(p[k], Wfc[t * DH + k], a);
        out[g * NC + t] = a;
    }
}

extern "C" void kernel_launch(void* const* d_in, const int* in_sizes, int n_in,
                              void* d_out, int out_size, void* d_ws, size_t ws_size,
                              hipStream_t stream) {
    const float* x     = (const float*)d_in[0];
    const int*   ei    = (const int*)d_in[1];
    const int*   batch = (const int*)d_in[2];
    const float* W1 = (const float*)d_in[3];
    const float* b1 = (const float*)d_in[4];
    const float* W2 = (const float*)d_in[5];
    const float* b2 = (const float*)d_in[6];
    const float* W3 = (const float*)d_in[7];
    const float* b3 = (const float*)d_in[8];
    const float* Wfc = (const float*)d_in[9];
    const float* bfc = (const float*)d_in[10];
    float* out = (float*)d_out;

    char* wp = (char*)d_ws;
    auto alloc = [&](size_t bytes) {
        char* q = wp;
        wp += (bytes + 511) & ~(size_t)511;
        return (void*)q;
    };
    int*   cursor  = (int*)alloc((size_t)NN * 4);               // true in-degree after pre
    int*   csr_src = (int*)alloc((size_t)NN * CAP * 4);         // bucket CSR
    float* sums    = (float*)alloc((size_t)NG * DH * 4);        // zeroed inside k_pre
    _Float16* xh   = (_Float16*)alloc((size_t)NN * DIN * 2);
    _Float16* tb   = (_Float16*)alloc((size_t)NN * DH * 2);
    _Float16* hA   = (_Float16*)alloc((size_t)NN * DH * 2);
    _Float16* hB   = (_Float16*)alloc((size_t)NN * DH * 2);
    _Float16* w1h = (_Float16*)alloc((size_t)DH * DIN * 2);
    _Float16* w2h = (_Float16*)alloc((size_t)DH * DH * 2);
    _Float16* w3h = (_Float16*)alloc((size_t)DH * DH * 2);

    // only cursor must be zero before pre's atomics (120 KB)
    hipMemsetAsync(cursor, 0, (size_t)NN * 4, stream);

    k_pre<<<(P1MAX + 255) / 256, 256, 0, stream>>>(ei, cursor, csr_src, x, xh,
                                                   W1, W2, W3, w1h, w2h, w3h, sums);

    dim3 gg((NN + 63) / 64, 4);
    // h_l = relu((A.h_{l-1}) W^T + b)  [linearity reorder]
    k_agg<128><<<NN / 4, 256, 0, stream>>>(xh, tb, cursor, csr_src);
    k_gemm<128, false><<<gg, 256, 0, stream>>>(tb, w1h, b1, hA, nullptr, nullptr);
    k_agg<256><<<NN / 4, 256, 0, stream>>>(hA, tb, cursor, csr_src);
    k_gemm<256, false><<<gg, 256, 0, stream>>>(tb, w2h, b2, hB, nullptr, nullptr);
    k_agg<256><<<NN / 4, 256, 0, stream>>>(hB, tb, cursor, csr_src);
    k_gemm<256, true><<<gg, 256, 0, stream>>>(tb, w3h, b3, nullptr, batch, sums);  // + pool

    k_fc<<<NG, 64, 0, stream>>>(sums, batch, Wfc, bfc, out);
}